// Round 13
// baseline (67.385 us; speedup 1.0000x reference)
//
#include <hip/hip_runtime.h>

// Hybrid quantum autoencoder, light-cone-reduced (exact 5-qubit reduction).
// R6 -> R7: (a) 32 lanes per batch element (1 complex amp per lane; wires
// 0..4 = lane bits 0..4) -> 262144 threads = 4 waves/SIMD for latency hiding
// (R6 had exactly 1 wave/SIMD). (b) The 10 wave-uniform gate matrices are
// built once per block by threads 0..9 into LDS and consumed via broadcast
// ds_read_b128, removing 30 redundant sincos per thread. (c) MLP hidden
// vector goes through LDS instead of a 12x5 shfl butterfly.

__device__ __forceinline__ void fsincos(float x, float& s, float& c) {
    s = __sinf(x);   // native v_sin_f32
    c = __cosf(x);   // native v_cos_f32
}

__global__ __launch_bounds__(256) void qae_kernel(
    const float* __restrict__ inputs,   // (B,12) - only cols 0..4 used
    const float* __restrict__ qp,       // (2,12,3)
    const float* __restrict__ W1,       // (32,4)
    const float* __restrict__ b1,       // (32,)
    const float* __restrict__ W2,       // (12,32)
    const float* __restrict__ b2,       // (12,)
    float* __restrict__ out,            // (B,12)
    int B)
{
    __shared__ float ug[10][8];    // per-gate {u00r,u00i,u01r,u01i,u10r,u10i,u11r,u11i}
    __shared__ float hsh[8][32];   // per-element hidden vector

    const int t = threadIdx.x;

    // ---- gate-matrix precompute: 10 threads, one gate each ----
    if (t < 10) {
        int l = t / 5, w = t - 5 * l;
        const float* p = qp + (l * 12 + w) * 3;
        float phi = p[0], th = p[1], om = p[2];
        float st, ct, sha, cha, shb, chb;
        fsincos(0.5f * th, st, ct);
        fsincos(0.5f * (phi + om), sha, cha);
        fsincos(0.5f * (phi - om), shb, chb);
        // Rot = RZ(om) RY(th) RZ(phi)
        ug[t][0] =  cha * ct;  ug[t][1] = -sha * ct;   // u00
        ug[t][2] = -chb * st;  ug[t][3] = -shb * st;   // u01
        ug[t][4] =  chb * st;  ug[t][5] = -shb * st;   // u10
        ug[t][6] =  cha * ct;  ug[t][7] =  sha * ct;   // u11
    }

    const int gtid = blockIdx.x * 256 + t;
    const int e    = gtid >> 5;          // batch element
    const int g    = t & 31;             // amp index = lane bits 0..4 = wires 0..4
    const int eg   = t >> 5;             // element slot within block (0..7)
    const int ec   = (e < B) ? e : (B - 1);

    // ---- initial product state: RX(x_j)|0> = [cos(x/2), -i sin(x/2)] ----
    const float* x = inputs + (size_t)ec * 12;
    float4 xv = *reinterpret_cast<const float4*>(x);   // rows 48B, 16B-aligned
    float x4 = x[4];
    float s0,c0,s1,c1,s2,c2,s3,c3,s4,c4;
    fsincos(0.5f * xv.x, s0, c0);
    fsincos(0.5f * xv.y, s1, c1);
    fsincos(0.5f * xv.z, s2, c2);
    fsincos(0.5f * xv.w, s3, c3);
    fsincos(0.5f * x4,   s4, c4);
    float m = ((g & 1) ? s0 : c0) * ((g & 2) ? s1 : c1) * ((g & 4) ? s2 : c2)
            * ((g & 8) ? s3 : c3) * ((g & 16) ? s4 : c4);
    int pc = __popc(g) & 3;              // phase (-i)^popcount
    float ar = (pc == 0) ? m : ((pc == 2) ? -m : 0.0f);
    float ai = (pc == 1) ? -m : ((pc == 3) ? m : 0.0f);

    __syncthreads();   // gates ready

    // ---- 2 layers: Rot on wires 0..4, CNOT chain 0..3 ----
#pragma unroll
    for (int l = 0; l < 2; ++l) {
#pragma unroll
        for (int w = 0; w < 5; ++w) {
            const float* u = ug[l * 5 + w];
            float4 ua = *reinterpret_cast<const float4*>(u);     // u00, u01
            float4 ub = *reinterpret_cast<const float4*>(u + 4); // u10, u11
            bool hi = (g >> w) & 1;
            // mine-coeff = hi ? u11 : u00 ; partner-coeff = hi ? u10 : u01
            float cmr = hi ? ub.z : ua.x;
            float cmi = hi ? ub.w : ua.y;
            float ctr = hi ? ub.x : ua.z;
            float cti = hi ? ub.y : ua.w;
            float tr = __shfl_xor(ar, 1 << w, 64);
            float ti = __shfl_xor(ai, 1 << w, 64);
            float nr = cmr * ar - cmi * ai + ctr * tr - cti * ti;
            float ni = cmr * ai + cmi * ar + ctr * ti + cti * tr;
            ar = nr; ai = ni;
        }
        // CNOT(c, c+1): if bit_c(g)==1, amp comes from g ^ (1<<(c+1))
#pragma unroll
        for (int c = 0; c < 4; ++c) {
            float tr = __shfl_xor(ar, 2 << c, 64);
            float ti = __shfl_xor(ai, 2 << c, 64);
            bool ctrl = (g >> c) & 1;
            ar = ctrl ? tr : ar;
            ai = ctrl ? ti : ai;
        }
    }

    // ---- Z expvals on wires 0..3: butterfly over the 32-lane group ----
    float p  = ar * ar + ai * ai;
    float l0 = (g & 1) ? -p : p;
    float l1 = (g & 2) ? -p : p;
    float l2 = (g & 4) ? -p : p;
    float l3 = (g & 8) ? -p : p;
#pragma unroll
    for (int mm = 1; mm <= 16; mm <<= 1) {
        l0 += __shfl_xor(l0, mm, 64);
        l1 += __shfl_xor(l1, mm, 64);
        l2 += __shfl_xor(l2, mm, 64);
        l3 += __shfl_xor(l3, mm, 64);
    }

    // ---- MLP layer 1: lane g computes hidden unit g ----
    float4 w1v = *reinterpret_cast<const float4*>(W1 + 4 * g);
    float h = fmaxf(b1[g] + l0 * w1v.x + l1 * w1v.y + l2 * w1v.z + l3 * w1v.w, 0.0f);
    hsh[eg][g] = h;
    __syncthreads();

    // ---- MLP layer 2: lanes g<12 each produce one output ----
    if (e < B && g < 12) {
        const float4* hv = reinterpret_cast<const float4*>(hsh[eg]);
        const float4* w2 = reinterpret_cast<const float4*>(W2 + 32 * g);
        float o = b2[g];
#pragma unroll
        for (int k = 0; k < 8; ++k) {
            float4 hk = hv[k];
            float4 wk = w2[k];
            o += hk.x * wk.x + hk.y * wk.y + hk.z * wk.z + hk.w * wk.w;
        }
        out[(size_t)e * 12 + g] = o;
    }
}

extern "C" void kernel_launch(void* const* d_in, const int* in_sizes, int n_in,
                              void* d_out, int out_size, void* d_ws, size_t ws_size,
                              hipStream_t stream) {
    const float* inputs = (const float*)d_in[0];
    const float* qp     = (const float*)d_in[1];
    const float* W1     = (const float*)d_in[2];
    const float* b1     = (const float*)d_in[3];
    const float* W2     = (const float*)d_in[4];
    const float* b2     = (const float*)d_in[5];
    float* out = (float*)d_out;

    int B = in_sizes[0] / 12;                  // 8192
    long long threads = (long long)B * 32;     // 32 lanes per element
    int block = 256;
    int grid = (int)((threads + block - 1) / block);  // 1024 -> 4 waves/SIMD
    qae_kernel<<<grid, block, 0, stream>>>(inputs, qp, W1, b1, W2, b2, out, B);
}